// Round 8
// baseline (689.204 us; speedup 1.0000x reference)
//
#include <hip/hip_runtime.h>

// BERT encoder block fwd. R8: GEMM retiled for occupancy-2 — BM=256,BN=128,BK=32,
// 8 waves x (64x64), acc 64 VGPR, LDS 48KB dbuf (2 blocks/CU), ONE barrier per
// K-tile (stage-next -> ds_read -> MFMA -> syncthreads). No LDS swizzle needed at
// 64B rows (uniform bank spread). Bet: co-resident block hides fill/drain/epilogue
// (R7 was 1 block/CU; ~25us/round of unhidden overhead). Epilogue still LDS-staged
// coalesced (2 batches of [128][128]).

typedef __attribute__((ext_vector_type(4))) float  f32x4;
typedef __attribute__((ext_vector_type(8))) short  s16x8;
typedef __attribute__((ext_vector_type(4))) short  s16x4;
typedef unsigned short u16;
typedef unsigned int   u32;

__device__ __forceinline__ float bf2f(short s) {
  u32 u = ((u32)(u16)s) << 16;
  float f; __builtin_memcpy(&f, &u, 4); return f;
}
__device__ __forceinline__ short f2bf(float f) {
  u32 u; __builtin_memcpy(&u, &f, 4);
  u32 r = (u + 0x7fffu + ((u >> 16) & 1u)) >> 16;   // RNE
  return (short)(u16)r;
}

// async global->LDS, 16B/lane; LDS dest must be wave-uniform base + lane*16
__device__ __forceinline__ void gload16(const void* g, void* l) {
  __builtin_amdgcn_global_load_lds(
      (const __attribute__((address_space(1))) u32*)g,
      (__attribute__((address_space(3))) u32*)l, 16, 0, 0);
}

// Epilogue MODE: 1 = +bias; 2 = relu(+bias); 3 = exp(scale*acc) [scores];
//               4 = acc * linv[z*M+row] [PV]; 5 = +bias, route col>>10 to three
//               [*,1024] outputs spaced 16777216 elems (fused QKV; BN=128 tiles
//               never straddle a 1024 boundary).
template<int MODE>
__global__ __launch_bounds__(512, 4)
void gemm256(const u16* __restrict__ A, const u16* __restrict__ BT,
             u16* __restrict__ C,
             const float* __restrict__ bias0, const float* __restrict__ bias1,
             const float* __restrict__ bias2, const float* __restrict__ linv,
             int M, int N, int K, float scale,
             long long sA, long long sB, long long sC) {
  // LDS map (u16 units): SA dbuf [2][8192] at 0; SB dbuf [2][4096] at 16384.
  // Epilogue reuses [0..16384) as [128][128] per batch. Total 24576 u16 = 48 KB.
  __shared__ u16 SMEM[24576];

  // T1: bijective XCD swizzle over flattened 3D grid (m204)
  const int gx = gridDim.x, gy = gridDim.y;
  const int nwg = gx * gy * gridDim.z;
  const int orig = (blockIdx.z * gy + blockIdx.y) * gx + blockIdx.x;
  const int q = nwg >> 3, r8 = nwg & 7;
  const int xcd = orig & 7, pos = orig >> 3;
  const int wg = (xcd < r8 ? xcd * (q + 1) : r8 * (q + 1) + (xcd - r8) * q) + pos;
  const int bz = wg / (gx * gy);
  const int rem = wg % (gx * gy);
  const long long bm = (long long)(rem / gx) * 256;
  const long long bn = (long long)(rem % gx) * 128;

  const char* Ag = (const char*)(A + (long long)bz * sA);
  const char* Bg = (const char*)(BT + (long long)bz * sB);
  u16* Cb = C + (long long)bz * sC;
  const long long ldb = (long long)K * 2;

  const int tid = threadIdx.x;
  const int lane = tid & 63, wid = tid >> 6;
  const int lr = lane & 15, kg = lane >> 4;
  const int wm = wid >> 1, wn = wid & 1;   // 4 x 2 wave grid, wave out 64x64
  const int NT = K >> 5;                   // BK = 32

  f32x4 acc[4][4] = {};

  // ---- staging helpers (linear LDS dest, linear global src) -----------------
  // A tile: 256 rows x 32 k = 16 KB -> 2 sweeps; B tile: 128 x 32 = 8 KB -> 1.
  const int oA0 = tid * 16, oA1 = (512 + tid) * 16, oB0 = tid * 16;
  const long long arow0 = bm + (oA0 >> 6), arow1 = bm + (oA1 >> 6);
  const long long brow0 = bn + (oB0 >> 6);
  const int akoff0 = oA0 & 63, akoff1 = oA1 & 63, bkoff0 = oB0 & 63;

#define STAGE(TT, CN) do { \
    char* sa_ = (char*)(SMEM + (CN) * 8192); \
    char* sb_ = (char*)(SMEM + 16384 + (CN) * 4096); \
    const long long kb_ = (long long)(TT) * 64; \
    gload16(Ag + arow0 * ldb + kb_ + akoff0, sa_ + oA0); \
    gload16(Ag + arow1 * ldb + kb_ + akoff1, sa_ + oA1); \
    gload16(Bg + brow0 * ldb + kb_ + bkoff0, sb_ + oB0); \
  } while (0)

  // prologue: tile 0 into buffer 0
  STAGE(0, 0);
  __syncthreads();

  for (int T = 0; T < NT; ++T) {
    const int c = T & 1, cn = c ^ 1;
    if (T + 1 < NT) STAGE(T + 1, cn);

    const char* pa = (const char*)(SMEM + c * 8192);
    const char* pb = (const char*)(SMEM + 16384 + c * 4096);
    s16x8 af[4], bfr[4];
#pragma unroll
    for (int mi = 0; mi < 4; ++mi)
      af[mi] = *(const s16x8*)(pa + ((wm * 64 + mi * 16 + lr) << 6) + (kg << 4));
#pragma unroll
    for (int nj = 0; nj < 4; ++nj)
      bfr[nj] = *(const s16x8*)(pb + ((wn * 64 + nj * 16 + lr) << 6) + (kg << 4));

    __builtin_amdgcn_s_setprio(1);
#pragma unroll
    for (int mi = 0; mi < 4; ++mi)
#pragma unroll
      for (int nj = 0; nj < 4; ++nj)
        acc[mi][nj] = __builtin_amdgcn_mfma_f32_16x16x32_bf16(af[mi], bfr[nj], acc[mi][nj], 0, 0, 0);
    __builtin_amdgcn_s_setprio(0);
    __syncthreads();   // vmcnt(0)+lgkm+barrier: next tile staged, all reads done
  }

  // ---- epilogue: 2 batches of 128 rows via LDS [128][128], coalesced stores.
  // LDS write swizzle: col' = col ^ (kg<<4), kg = (localrow>>2)&3; inverse on read.
  const long long zM = (long long)bz * M;
  u16* obase; long long ldc, bnl;
  const float* bptr = bias0;
  if (MODE == 5) {
    const int sel = (int)(bn >> 10);
    obase = C + (long long)sel * 16777216;
    ldc = 1024; bnl = bn & 1023;
    bptr = (sel == 0 ? bias0 : sel == 1 ? bias1 : bias2);
  } else { obase = Cb; ldc = N; bnl = bn; }

#pragma unroll
  for (int b = 0; b < 2; ++b) {
    if ((wm >> 1) == b) {
      const int rbase = (wm & 1) * 64;
#pragma unroll
      for (int nj = 0; nj < 4; ++nj) {
        const int col = wn * 64 + nj * 16 + lr;           // local col 0..127
        float bv = 0.f;
        if (MODE == 1 || MODE == 2 || MODE == 5) bv = bptr[bnl + col];
#pragma unroll
        for (int mi = 0; mi < 4; ++mi) {
          const int r0 = rbase + mi * 16 + kg * 4;        // batch-local row
#pragma unroll
          for (int r = 0; r < 4; ++r) {
            float v = acc[mi][nj][r];
            if (MODE == 1 || MODE == 2 || MODE == 5) v = v * scale + bv;
            if (MODE == 2) v = fmaxf(v, 0.f);
            if (MODE == 3) v = __expf(v * scale);
            if (MODE == 4) v = v * linv[zM + bm + b * 128 + r0 + r];
            SMEM[(r0 + r) * 128 + (col ^ (kg << 4))] = (u16)f2bf(v);
          }
        }
      }
    }
    __syncthreads();
#pragma unroll
    for (int i = 0; i < 4; ++i) {
      const int o   = (i * 512 + tid) * 16;        // byte offset in 32 KiB batch
      const int row = o >> 8;                      // batch-local row (256 B/row)
      const int wb  = o & 255;                     // byte-in-row
      const int gs  = (wb >> 4) ^ ((((row) >> 2) & 3) << 1);  // inverse swizzle
      s16x8 d = *(const s16x8*)((const char*)SMEM + row * 256 + (gs << 4));
      *(s16x8*)((char*)obase + (((long long)bm + b * 128 + row) * ldc + bnl) * 2 + wb) = d;
    }
    __syncthreads();
  }
#undef STAGE
}

// ---------------------------------------------------------------- cast x -> bf16
__global__ __launch_bounds__(256) void cast_f32_bf16(const float* __restrict__ in,
                                                     u16* __restrict__ out) {
  long long i = (long long)blockIdx.x * 256 + threadIdx.x;
  f32x4 v = ((const f32x4*)in)[i];
  s16x4 o;
#pragma unroll
  for (int j = 0; j < 4; j++) o[j] = f2bf(v[j]);
  ((s16x4*)out)[i] = o;
}

// ------------------------------------------------- transpose fp32 [R,C] -> bf16 [C,R]
__global__ __launch_bounds__(256) void transpose_f32_bf16(const float* __restrict__ in,
                                                          u16* __restrict__ out,
                                                          int R, int C) {
  __shared__ float tile[32][33];
  const int tx = threadIdx.x, ty = threadIdx.y;
  const int r0 = blockIdx.y * 32, c0 = blockIdx.x * 32;
#pragma unroll
  for (int i = 0; i < 32; i += 8)
    tile[ty + i][tx] = in[(long long)(r0 + ty + i) * C + (c0 + tx)];
  __syncthreads();
#pragma unroll
  for (int i = 0; i < 32; i += 8)
    out[(long long)(c0 + ty + i) * R + (r0 + tx)] = (u16)f2bf(tile[tx][ty + i]);
}

// ------------------------------------------------- transpose bf16 [R,C] -> bf16 [C,R] (batched)
__global__ __launch_bounds__(256) void transpose_bf16_bf16(const u16* __restrict__ in,
                                                           u16* __restrict__ out,
                                                           int R, int C,
                                                           long long isb, long long osb) {
  __shared__ u16 tile[32][33];
  in  += (long long)blockIdx.z * isb;
  out += (long long)blockIdx.z * osb;
  const int tx = threadIdx.x, ty = threadIdx.y;
  const int r0 = blockIdx.y * 32, c0 = blockIdx.x * 32;
#pragma unroll
  for (int i = 0; i < 32; i += 8)
    tile[ty + i][tx] = in[(long long)(r0 + ty + i) * C + (c0 + tx)];
  __syncthreads();
#pragma unroll
  for (int i = 0; i < 32; i += 8)
    out[(long long)(c0 + ty + i) * R + (r0 + tx)] = tile[tx][ty + i];
}

// ---------------------------------------------------------------- row sum -> 1/l (2048 cols)
__global__ __launch_bounds__(256) void rowinv2048(const u16* __restrict__ P,
                                                  float* __restrict__ linv) {
  const long long row = blockIdx.x;
  const u16* p = P + row * 2048;
  const int t = threadIdx.x;
  s16x8 raw = *(const s16x8*)&p[t * 8];
  float s = 0.f;
#pragma unroll
  for (int j = 0; j < 8; j++) s += bf2f(raw[j]);
#pragma unroll
  for (int off = 32; off > 0; off >>= 1) s += __shfl_xor(s, off);
  __shared__ float red[4];
  if ((t & 63) == 0) red[t >> 6] = s;
  __syncthreads();
  if (t == 0) {
    s = (red[0] + red[1]) + (red[2] + red[3]);
    linv[row] = 1.0f / s;
  }
}

// ---------------------------------------------------------------- LN(x_f32 + a_bf16) -> bf16
__global__ __launch_bounds__(256) void ln_add_f32bf16(const float* __restrict__ x,
                                                      const u16* __restrict__ a,
                                                      const float* __restrict__ g,
                                                      const float* __restrict__ be,
                                                      u16* __restrict__ out) {
  const long long row = blockIdx.x;
  const int t = threadIdx.x;
  f32x4 xv = ((const f32x4*)(x + row * 1024))[t];
  s16x4 av = ((const s16x4*)(a + row * 1024))[t];
  float v[4]; float sum = 0.f, ss = 0.f;
#pragma unroll
  for (int j = 0; j < 4; j++) { v[j] = xv[j] + bf2f(av[j]); sum += v[j]; ss += v[j] * v[j]; }
#pragma unroll
  for (int off = 32; off > 0; off >>= 1) { sum += __shfl_xor(sum, off); ss += __shfl_xor(ss, off); }
  __shared__ float red[8];
  if ((t & 63) == 0) { red[t >> 6] = sum; red[4 + (t >> 6)] = ss; }
  __syncthreads();
  sum = (red[0] + red[1]) + (red[2] + red[3]);
  ss  = (red[4] + red[5]) + (red[6] + red[7]);
  const float mu   = sum * (1.f / 1024.f);
  const float var  = ss * (1.f / 1024.f) - mu * mu;
  const float rstd = rsqrtf(var + 1e-5f);
  s16x4 o;
#pragma unroll
  for (int j = 0; j < 4; j++) {
    const int c = t * 4 + j;
    o[j] = f2bf((v[j] - mu) * rstd * g[c] + be[c]);
  }
  *(s16x4*)&out[row * 1024 + t * 4] = o;
}

// ---------------------------------------------------------------- LN(h_bf16 + f_bf16) -> fp32
__global__ __launch_bounds__(256) void ln_add_bf16bf16(const u16* __restrict__ h,
                                                       const u16* __restrict__ f,
                                                       const float* __restrict__ g,
                                                       const float* __restrict__ be,
                                                       float* __restrict__ out) {
  const long long row = blockIdx.x;
  const int t = threadIdx.x;
  s16x4 hv = ((const s16x4*)(h + row * 1024))[t];
  s16x4 fv = ((const s16x4*)(f + row * 1024))[t];
  float v[4]; float sum = 0.f, ss = 0.f;
#pragma unroll
  for (int j = 0; j < 4; j++) { v[j] = bf2f(hv[j]) + bf2f(fv[j]); sum += v[j]; ss += v[j] * v[j]; }
#pragma unroll
  for (int off = 32; off > 0; off >>= 1) { sum += __shfl_xor(sum, off); ss += __shfl_xor(ss, off); }
  __shared__ float red[8];
  if ((t & 63) == 0) { red[t >> 6] = sum; red[4 + (t >> 6)] = ss; }
  __syncthreads();
  sum = (red[0] + red[1]) + (red[2] + red[3]);
  ss  = (red[4] + red[5]) + (red[6] + red[7]);
  const float mu   = sum * (1.f / 1024.f);
  const float var  = ss * (1.f / 1024.f) - mu * mu;
  const float rstd = rsqrtf(var + 1e-5f);
  f32x4 o;
#pragma unroll
  for (int j = 0; j < 4; j++) {
    const int c = t * 4 + j;
    o[j] = (v[j] - mu) * rstd * g[c] + be[c];
  }
  ((f32x4*)(out + row * 1024))[t] = o;
}

// ---------------------------------------------------------------- launcher
extern "C" void kernel_launch(void* const* d_in, const int* in_sizes, int n_in,
                              void* d_out, int out_size, void* d_ws, size_t ws_size,
                              hipStream_t stream) {
  const float* x   = (const float*)d_in[0];
  const float* Wq  = (const float*)d_in[1];
  const float* bq  = (const float*)d_in[2];
  const float* Wk  = (const float*)d_in[3];
  const float* bk  = (const float*)d_in[4];
  const float* Wv  = (const float*)d_in[5];
  const float* bv  = (const float*)d_in[6];
  const float* Wo  = (const float*)d_in[7];
  const float* bo  = (const float*)d_in[8];
  const float* g1  = (const float*)d_in[9];
  const float* b1  = (const float*)d_in[10];
  const float* g2  = (const float*)d_in[11];
  const float* b2  = (const float*)d_in[12];
  const float* W1  = (const float*)d_in[13];
  const float* bf1 = (const float*)d_in[14];
  const float* W2  = (const float*)d_in[15];
  const float* bf2 = (const float*)d_in[16];
  float* out = (float*)d_out;

  // workspace layout (bytes), ~248 MiB, with aliasing.
  // weights 0..25165824 (WQT/WKT/WVT contiguous = fused [3072,1024]); XB 32MiB;
  // Q 32MiB; K 32MiB; V 32MiB; VT 32MiB; S 64MiB.
  // Aliases: AO->XB, AO2->Q, H->K, HID->[V..S end] (128MiB), FFN->XB, linv->Q start.
  char* ws = (char*)d_ws;
  u16* wsWQT = (u16*)(ws + 0);           // fused QKV weight base [3072,1024]
  u16* wsWKT = (u16*)(ws + 2097152);
  u16* wsWVT = (u16*)(ws + 4194304);
  u16* wsWOT = (u16*)(ws + 6291456);
  u16* wsW1T = (u16*)(ws + 8388608);     // [4096,1024] bf16, 8 MiB
  u16* wsW2T = (u16*)(ws + 16777216);    // [1024,4096] bf16, 8 MiB
  u16* wsXB  = (u16*)(ws + 25165824);    // [16384,1024] bf16 tokens, 32 MiB
  u16* wsQ   = (u16*)(ws + 58720256);    // Q/K/V contiguous (QKV epilogue routing)
  u16* wsK   = (u16*)(ws + 92274688);
  u16* wsV   = (u16*)(ws + 125829120);
  u16* wsVT  = (u16*)(ws + 159383552);   // [8][1024,2048] bf16, 32 MiB
  u16* wsS   = (u16*)(ws + 192937984);   // [8][2048,2048] bf16 P~ = exp(s), 64 MiB
  u16* wsAO  = wsXB;
  u16* wsAO2 = wsQ;
  u16* wsH   = wsK;
  u16* wsHID = wsV;                      // [16384,4096] bf16, 128 MiB (covers V,VT,S)
  u16* wsFFN = wsXB;
  float* wsLINV = (float*)wsQ;           // 64 KiB; Q dead during PV, AO2 written after

  const dim3 tb(32, 8, 1);
  const float inv_sqrt_e = 0.03125f;   // 1/sqrt(1024)
  const float* nf = nullptr;

  // 1) cast x -> bf16
  cast_f32_bf16<<<16384, 256, 0, stream>>>(x, wsXB);

  // 2) weights -> bf16 transposed [N,K]  (Wq/Wk/Wv land contiguous)
  transpose_f32_bf16<<<dim3(32, 32, 1),  tb, 0, stream>>>(Wq, wsWQT, 1024, 1024);
  transpose_f32_bf16<<<dim3(32, 32, 1),  tb, 0, stream>>>(Wk, wsWKT, 1024, 1024);
  transpose_f32_bf16<<<dim3(32, 32, 1),  tb, 0, stream>>>(Wv, wsWVT, 1024, 1024);
  transpose_f32_bf16<<<dim3(32, 32, 1),  tb, 0, stream>>>(Wo, wsWOT, 1024, 1024);
  transpose_f32_bf16<<<dim3(128, 32, 1), tb, 0, stream>>>(W1, wsW1T, 1024, 4096);
  transpose_f32_bf16<<<dim3(32, 128, 1), tb, 0, stream>>>(W2, wsW2T, 4096, 1024);

  // 3) fused QKV: [16384,1024] x [3072,1024]^T, epilogue routes to Q/K/V + bias
  gemm256<5><<<dim3(24, 64, 1), 512, 0, stream>>>(wsXB, wsWQT, wsQ, bq, bk, bv, nf,
                                                  16384, 3072, 1024, 1.f, 0, 0, 0);

  // 4) V -> V^T per batch: [2048,1024] -> [1024,2048]
  transpose_bf16_bf16<<<dim3(32, 64, 8), tb, 0, stream>>>(wsV, wsVT, 2048, 1024, 2048LL * 1024, 1024LL * 2048);

  // 5) P~ = exp(Q K^T / 32) : batched, epilogue exp (no max-sub; |s| <= ~2)
  gemm256<3><<<dim3(16, 8, 8), 512, 0, stream>>>(wsQ, wsK, wsS, nf, nf, nf, nf,
                                                 2048, 2048, 1024, inv_sqrt_e,
                                                 2048LL * 1024, 2048LL * 1024, 2048LL * 2048);
  // 6) linv[row] = 1 / rowsum(P~)
  rowinv2048<<<16384, 256, 0, stream>>>(wsS, wsLINV);

  // 7) attn_out = (P~ V) * linv : batched, epilogue row-normalize (per-batch linv)
  gemm256<4><<<dim3(8, 8, 8), 512, 0, stream>>>(wsS, wsVT, wsAO, nf, nf, nf, wsLINV,
                                                2048, 1024, 2048, 1.f,
                                                2048LL * 2048, 1024LL * 2048, 2048LL * 1024);
  // 8) out-proj  (AO2 overwrites linv region only after PV completed, stream-ordered)
  gemm256<1><<<dim3(8, 64, 1), 512, 0, stream>>>(wsAO, wsWOT, wsAO2, bo, nf, nf, nf,
                                                 16384, 1024, 1024, 1.f, 0, 0, 0);

  // 9) h = LN(x + AO2)
  ln_add_f32bf16<<<16384, 256, 0, stream>>>(x, wsAO2, g1, b1, wsH);

  // 10) HID = relu(h W1 + bf1) : [16384,1024] x [1024,4096]
  gemm256<2><<<dim3(32, 64, 1), 512, 0, stream>>>(wsH, wsW1T, wsHID, bf1, nf, nf, nf,
                                                  16384, 4096, 1024, 1.f, 0, 0, 0);

  // 11) FFN = HID W2 + bf2 : [16384,4096] x [4096,1024]
  gemm256<1><<<dim3(8, 64, 1), 512, 0, stream>>>(wsHID, wsW2T, wsFFN, bf2, nf, nf, nf,
                                                 16384, 1024, 4096, 1.f, 0, 0, 0);

  // 12) out = LN(h + FFN), fp32
  ln_add_bf16bf16<<<16384, 256, 0, stream>>>(wsH, wsFFN, g2, b2, out);

  (void)in_sizes; (void)n_in; (void)out_size; (void)ws_size;
}

// Round 9
// 687.538 us; speedup vs baseline: 1.0024x; 1.0024x over previous
//
#include <hip/hip_runtime.h>

// BERT encoder block fwd. R9 = R8 tile (BM256/BN128/BK32, 8 waves, occ-2) with the
// two R8 defects fixed:
//  (a) LDS XOR swizzle for 64B rows: logical (row,j) at j ^ (((row>>1)&3)<<4);
//      staging = linear LDS dest + inverse-swizzled GLOBAL source (rule #21).
//      -> any 8 consecutive lanes hit 8 distinct 4-bank groups (conflict-free).
//  (b) triple-buffered staging + counted vmcnt(3): one barrier/K-tile, loads never
//      drained to 0 mid-loop (T4). LDS 72KB -> still 2 blocks/CU.
// Epilogue LDS-staged coalesced stores kept from R7/R8.

typedef __attribute__((ext_vector_type(4))) float  f32x4;
typedef __attribute__((ext_vector_type(8))) short  s16x8;
typedef __attribute__((ext_vector_type(4))) short  s16x4;
typedef unsigned short u16;
typedef unsigned int   u32;

__device__ __forceinline__ float bf2f(short s) {
  u32 u = ((u32)(u16)s) << 16;
  float f; __builtin_memcpy(&f, &u, 4); return f;
}
__device__ __forceinline__ short f2bf(float f) {
  u32 u; __builtin_memcpy(&u, &f, 4);
  u32 r = (u + 0x7fffu + ((u >> 16) & 1u)) >> 16;   // RNE
  return (short)(u16)r;
}

// async global->LDS, 16B/lane; LDS dest must be wave-uniform base + lane*16
__device__ __forceinline__ void gload16(const void* g, void* l) {
  __builtin_amdgcn_global_load_lds(
      (const __attribute__((address_space(1))) u32*)g,
      (__attribute__((address_space(3))) u32*)l, 16, 0, 0);
}

// Epilogue MODE: 1 = +bias; 2 = relu(+bias); 3 = exp(scale*acc) [scores];
//               4 = acc * linv[z*M+row] [PV]; 5 = +bias, route col>>10 to three
//               [*,1024] outputs spaced 16777216 elems (fused QKV).
template<int MODE>
__global__ __launch_bounds__(512, 4)
void gemm256(const u16* __restrict__ A, const u16* __restrict__ BT,
             u16* __restrict__ C,
             const float* __restrict__ bias0, const float* __restrict__ bias1,
             const float* __restrict__ bias2, const float* __restrict__ linv,
             int M, int N, int K, float scale,
             long long sA, long long sB, long long sC) {
  // LDS map (u16): SA tribuf [3][8192] at 0 (48KB); SB tribuf [3][4096] at 24576
  // (24KB). Total 36864 u16 = 72 KB -> 2 blocks/CU. Epilogue reuses [0..16384).
  __shared__ u16 SMEM[36864];

  // T1: bijective XCD swizzle over flattened 3D grid (m204)
  const int gx = gridDim.x, gy = gridDim.y;
  const int nwg = gx * gy * gridDim.z;
  const int orig = (blockIdx.z * gy + blockIdx.y) * gx + blockIdx.x;
  const int q = nwg >> 3, r8 = nwg & 7;
  const int xcd = orig & 7, pos = orig >> 3;
  const int wg = (xcd < r8 ? xcd * (q + 1) : r8 * (q + 1) + (xcd - r8) * q) + pos;
  const int bz = wg / (gx * gy);
  const int rem = wg % (gx * gy);
  const long long bm = (long long)(rem / gx) * 256;
  const long long bn = (long long)(rem % gx) * 128;

  const char* Ag = (const char*)(A + (long long)bz * sA);
  const char* Bg = (const char*)(BT + (long long)bz * sB);
  u16* Cb = C + (long long)bz * sC;
  const long long ldb = (long long)K * 2;

  const int tid = threadIdx.x;
  const int lane = tid & 63, wid = tid >> 6;
  const int lr = lane & 15, kg = lane >> 4;
  const int wm = wid >> 1, wn = wid & 1;   // 4 x 2 wave grid, wave out 64x64
  const int NT = K >> 5;                   // BK = 32

  f32x4 acc[4][4] = {};

  // ---- staging: linear LDS dest, inverse-swizzled global source --------------
  // A tile 16KB (2 sweeps of 512x16B), B tile 8KB (1 sweep). LDS row = 64B.
  const int oA0 = tid * 16, oA1 = (512 + tid) * 16, oB0 = tid * 16;
  const int rA0 = oA0 >> 6, rA1 = oA1 >> 6, rB0 = oB0 >> 6;      // LDS-local rows
  const long long arow0 = bm + rA0, arow1 = bm + rA1;
  const long long brow0 = bn + rB0;
  const int asrc0 = (oA0 & 63) ^ (((rA0 >> 1) & 3) << 4);
  const int asrc1 = (oA1 & 63) ^ (((rA1 >> 1) & 3) << 4);
  const int bsrc0 = (oB0 & 63) ^ (((rB0 >> 1) & 3) << 4);

#define STAGE(TT, CC) do { \
    char* sa_ = (char*)(SMEM + (CC) * 8192); \
    char* sb_ = (char*)(SMEM + 24576 + (CC) * 4096); \
    const long long kb_ = (long long)(TT) * 64; \
    gload16(Ag + arow0 * ldb + kb_ + asrc0, sa_ + oA0); \
    gload16(Ag + arow1 * ldb + kb_ + asrc1, sa_ + oA1); \
    gload16(Bg + brow0 * ldb + kb_ + bsrc0, sb_ + oB0); \
  } while (0)

  // prologue: tiles 0,1 into buffers 0,1 (6 loads in flight)
  STAGE(0, 0);
  STAGE(1, 1);

  int c = 0;            // buffer holding tile T
  for (int T = 0; T < NT; ++T) {
    if (T + 1 < NT) { asm volatile("s_waitcnt vmcnt(3)"); }
    else            { asm volatile("s_waitcnt vmcnt(0)"); }
    __builtin_amdgcn_s_barrier();      // all waves: tile T staged, tile T-1 reads done
    __builtin_amdgcn_sched_barrier(0);

    if (T + 2 < NT) STAGE(T + 2, (T + 2) % 3);

    const char* pa = (const char*)(SMEM + c * 8192);
    const char* pb = (const char*)(SMEM + 24576 + c * 4096);
    s16x8 af[4], bfr[4];
#pragma unroll
    for (int mi = 0; mi < 4; ++mi) {
      const int row_ = wm * 64 + mi * 16 + lr;
      af[mi] = *(const s16x8*)(pa + (row_ << 6) + ((kg ^ ((row_ >> 1) & 3)) << 4));
    }
#pragma unroll
    for (int nj = 0; nj < 4; ++nj) {
      const int row_ = wn * 64 + nj * 16 + lr;
      bfr[nj] = *(const s16x8*)(pb + (row_ << 6) + ((kg ^ ((row_ >> 1) & 3)) << 4));
    }

    __builtin_amdgcn_s_setprio(1);
#pragma unroll
    for (int mi = 0; mi < 4; ++mi)
#pragma unroll
      for (int nj = 0; nj < 4; ++nj)
        acc[mi][nj] = __builtin_amdgcn_mfma_f32_16x16x32_bf16(af[mi], bfr[nj], acc[mi][nj], 0, 0, 0);
    __builtin_amdgcn_s_setprio(0);

    c = (c + 1) % 3;
  }
  __syncthreads();   // all reads done before SMEM reuse by epilogue

  // ---- epilogue: 2 batches of 128 rows via LDS [128][128], coalesced stores.
  // LDS write swizzle: col' = col ^ (kg<<4), kg = (localrow>>2)&3; inverse on read.
  const long long zM = (long long)bz * M;
  u16* obase; long long ldc, bnl;
  const float* bptr = bias0;
  if (MODE == 5) {
    const int sel = (int)(bn >> 10);
    obase = C + (long long)sel * 16777216;
    ldc = 1024; bnl = bn & 1023;
    bptr = (sel == 0 ? bias0 : sel == 1 ? bias1 : bias2);
  } else { obase = Cb; ldc = N; bnl = bn; }

#pragma unroll
  for (int b = 0; b < 2; ++b) {
    if ((wm >> 1) == b) {
      const int rbase = (wm & 1) * 64;
#pragma unroll
      for (int nj = 0; nj < 4; ++nj) {
        const int col = wn * 64 + nj * 16 + lr;           // local col 0..127
        float bv = 0.f;
        if (MODE == 1 || MODE == 2 || MODE == 5) bv = bptr[bnl + col];
#pragma unroll
        for (int mi = 0; mi < 4; ++mi) {
          const int r0 = rbase + mi * 16 + kg * 4;        // batch-local row
#pragma unroll
          for (int r = 0; r < 4; ++r) {
            float v = acc[mi][nj][r];
            if (MODE == 1 || MODE == 2 || MODE == 5) v = v * scale + bv;
            if (MODE == 2) v = fmaxf(v, 0.f);
            if (MODE == 3) v = __expf(v * scale);
            if (MODE == 4) v = v * linv[zM + bm + b * 128 + r0 + r];
            SMEM[(r0 + r) * 128 + (col ^ (kg << 4))] = (u16)f2bf(v);
          }
        }
      }
    }
    __syncthreads();
#pragma unroll
    for (int i = 0; i < 4; ++i) {
      const int o   = (i * 512 + tid) * 16;        // byte offset in 32 KiB batch
      const int row = o >> 8;                      // batch-local row (256 B/row)
      const int wb  = o & 255;                     // byte-in-row
      const int gs  = (wb >> 4) ^ ((((row) >> 2) & 3) << 1);  // inverse swizzle
      s16x8 d = *(const s16x8*)((const char*)SMEM + row * 256 + (gs << 4));
      *(s16x8*)((char*)obase + (((long long)bm + b * 128 + row) * ldc + bnl) * 2 + wb) = d;
    }
    __syncthreads();
  }
#undef STAGE
}

// ---------------------------------------------------------------- cast x -> bf16
__global__ __launch_bounds__(256) void cast_f32_bf16(const float* __restrict__ in,
                                                     u16* __restrict__ out) {
  long long i = (long long)blockIdx.x * 256 + threadIdx.x;
  f32x4 v = ((const f32x4*)in)[i];
  s16x4 o;
#pragma unroll
  for (int j = 0; j < 4; j++) o[j] = f2bf(v[j]);
  ((s16x4*)out)[i] = o;
}

// ------------------------------------------------- transpose fp32 [R,C] -> bf16 [C,R]
__global__ __launch_bounds__(256) void transpose_f32_bf16(const float* __restrict__ in,
                                                          u16* __restrict__ out,
                                                          int R, int C) {
  __shared__ float tile[32][33];
  const int tx = threadIdx.x, ty = threadIdx.y;
  const int r0 = blockIdx.y * 32, c0 = blockIdx.x * 32;
#pragma unroll
  for (int i = 0; i < 32; i += 8)
    tile[ty + i][tx] = in[(long long)(r0 + ty + i) * C + (c0 + tx)];
  __syncthreads();
#pragma unroll
  for (int i = 0; i < 32; i += 8)
    out[(long long)(c0 + ty + i) * R + (r0 + tx)] = (u16)f2bf(tile[tx][ty + i]);
}

// ------------------------------------------------- transpose bf16 [R,C] -> bf16 [C,R] (batched)
__global__ __launch_bounds__(256) void transpose_bf16_bf16(const u16* __restrict__ in,
                                                           u16* __restrict__ out,
                                                           int R, int C,
                                                           long long isb, long long osb) {
  __shared__ u16 tile[32][33];
  in  += (long long)blockIdx.z * isb;
  out += (long long)blockIdx.z * osb;
  const int tx = threadIdx.x, ty = threadIdx.y;
  const int r0 = blockIdx.y * 32, c0 = blockIdx.x * 32;
#pragma unroll
  for (int i = 0; i < 32; i += 8)
    tile[ty + i][tx] = in[(long long)(r0 + ty + i) * C + (c0 + tx)];
  __syncthreads();
#pragma unroll
  for (int i = 0; i < 32; i += 8)
    out[(long long)(c0 + ty + i) * R + (r0 + tx)] = tile[tx][ty + i];
}

// ---------------------------------------------------------------- row sum -> 1/l (2048 cols)
__global__ __launch_bounds__(256) void rowinv2048(const u16* __restrict__ P,
                                                  float* __restrict__ linv) {
  const long long row = blockIdx.x;
  const u16* p = P + row * 2048;
  const int t = threadIdx.x;
  s16x8 raw = *(const s16x8*)&p[t * 8];
  float s = 0.f;
#pragma unroll
  for (int j = 0; j < 8; j++) s += bf2f(raw[j]);
#pragma unroll
  for (int off = 32; off > 0; off >>= 1) s += __shfl_xor(s, off);
  __shared__ float red[4];
  if ((t & 63) == 0) red[t >> 6] = s;
  __syncthreads();
  if (t == 0) {
    s = (red[0] + red[1]) + (red[2] + red[3]);
    linv[row] = 1.0f / s;
  }
}

// ---------------------------------------------------------------- LN(x_f32 + a_bf16) -> bf16
__global__ __launch_bounds__(256) void ln_add_f32bf16(const float* __restrict__ x,
                                                      const u16* __restrict__ a,
                                                      const float* __restrict__ g,
                                                      const float* __restrict__ be,
                                                      u16* __restrict__ out) {
  const long long row = blockIdx.x;
  const int t = threadIdx.x;
  f32x4 xv = ((const f32x4*)(x + row * 1024))[t];
  s16x4 av = ((const s16x4*)(a + row * 1024))[t];
  float v[4]; float sum = 0.f, ss = 0.f;
#pragma unroll
  for (int j = 0; j < 4; j++) { v[j] = xv[j] + bf2f(av[j]); sum += v[j]; ss += v[j] * v[j]; }
#pragma unroll
  for (int off = 32; off > 0; off >>= 1) { sum += __shfl_xor(sum, off); ss += __shfl_xor(ss, off); }
  __shared__ float red[8];
  if ((t & 63) == 0) { red[t >> 6] = sum; red[4 + (t >> 6)] = ss; }
  __syncthreads();
  sum = (red[0] + red[1]) + (red[2] + red[3]);
  ss  = (red[4] + red[5]) + (red[6] + red[7]);
  const float mu   = sum * (1.f / 1024.f);
  const float var  = ss * (1.f / 1024.f) - mu * mu;
  const float rstd = rsqrtf(var + 1e-5f);
  s16x4 o;
#pragma unroll
  for (int j = 0; j < 4; j++) {
    const int c = t * 4 + j;
    o[j] = f2bf((v[j] - mu) * rstd * g[c] + be[c]);
  }
  *(s16x4*)&out[row * 1024 + t * 4] = o;
}

// ---------------------------------------------------------------- LN(h_bf16 + f_bf16) -> fp32
__global__ __launch_bounds__(256) void ln_add_bf16bf16(const u16* __restrict__ h,
                                                       const u16* __restrict__ f,
                                                       const float* __restrict__ g,
                                                       const float* __restrict__ be,
                                                       float* __restrict__ out) {
  const long long row = blockIdx.x;
  const int t = threadIdx.x;
  s16x4 hv = ((const s16x4*)(h + row * 1024))[t];
  s16x4 fv = ((const s16x4*)(f + row * 1024))[t];
  float v[4]; float sum = 0.f, ss = 0.f;
#pragma unroll
  for (int j = 0; j < 4; j++) { v[j] = bf2f(hv[j]) + bf2f(fv[j]); sum += v[j]; ss += v[j] * v[j]; }
#pragma unroll
  for (int off = 32; off > 0; off >>= 1) { sum += __shfl_xor(sum, off); ss += __shfl_xor(ss, off); }
  __shared__ float red[8];
  if ((t & 63) == 0) { red[t >> 6] = sum; red[4 + (t >> 6)] = ss; }
  __syncthreads();
  sum = (red[0] + red[1]) + (red[2] + red[3]);
  ss  = (red[4] + red[5]) + (red[6] + red[7]);
  const float mu   = sum * (1.f / 1024.f);
  const float var  = ss * (1.f / 1024.f) - mu * mu;
  const float rstd = rsqrtf(var + 1e-5f);
  f32x4 o;
#pragma unroll
  for (int j = 0; j < 4; j++) {
    const int c = t * 4 + j;
    o[j] = (v[j] - mu) * rstd * g[c] + be[c];
  }
  ((f32x4*)(out + row * 1024))[t] = o;
}

// ---------------------------------------------------------------- launcher
extern "C" void kernel_launch(void* const* d_in, const int* in_sizes, int n_in,
                              void* d_out, int out_size, void* d_ws, size_t ws_size,
                              hipStream_t stream) {
  const float* x   = (const float*)d_in[0];
  const float* Wq  = (const float*)d_in[1];
  const float* bq  = (const float*)d_in[2];
  const float* Wk  = (const float*)d_in[3];
  const float* bk  = (const float*)d_in[4];
  const float* Wv  = (const float*)d_in[5];
  const float* bv  = (const float*)d_in[6];
  const float* Wo  = (const float*)d_in[7];
  const float* bo  = (const float*)d_in[8];
  const float* g1  = (const float*)d_in[9];
  const float* b1  = (const float*)d_in[10];
  const float* g2  = (const float*)d_in[11];
  const float* b2  = (const float*)d_in[12];
  const float* W1  = (const float*)d_in[13];
  const float* bf1 = (const float*)d_in[14];
  const float* W2  = (const float*)d_in[15];
  const float* bf2 = (const float*)d_in[16];
  float* out = (float*)d_out;

  // workspace layout (bytes), ~248 MiB, with aliasing.
  // weights 0..25165824 (WQT/WKT/WVT contiguous = fused [3072,1024]); XB 32MiB;
  // Q 32MiB; K 32MiB; V 32MiB; VT 32MiB; S 64MiB.
  // Aliases: AO->XB, AO2->Q, H->K, HID->[V..S end] (128MiB), FFN->XB, linv->Q start.
  char* ws = (char*)d_ws;
  u16* wsWQT = (u16*)(ws + 0);           // fused QKV weight base [3072,1024]
  u16* wsWKT = (u16*)(ws + 2097152);
  u16* wsWVT = (u16*)(ws + 4194304);
  u16* wsWOT = (u16*)(ws + 6291456);
  u16* wsW1T = (u16*)(ws + 8388608);     // [4096,1024] bf16, 8 MiB
  u16* wsW2T = (u16*)(ws + 16777216);    // [1024,4096] bf16, 8 MiB
  u16* wsXB  = (u16*)(ws + 25165824);    // [16384,1024] bf16 tokens, 32 MiB
  u16* wsQ   = (u16*)(ws + 58720256);    // Q/K/V contiguous (QKV epilogue routing)
  u16* wsK   = (u16*)(ws + 92274688);
  u16* wsV   = (u16*)(ws + 125829120);
  u16* wsVT  = (u16*)(ws + 159383552);   // [8][1024,2048] bf16, 32 MiB
  u16* wsS   = (u16*)(ws + 192937984);   // [8][2048,2048] bf16 P~ = exp(s), 64 MiB
  u16* wsAO  = wsXB;
  u16* wsAO2 = wsQ;
  u16* wsH   = wsK;
  u16* wsHID = wsV;                      // [16384,4096] bf16, 128 MiB (covers V,VT,S)
  u16* wsFFN = wsXB;
  float* wsLINV = (float*)wsQ;           // 64 KiB; Q dead during PV, AO2 written after

  const dim3 tb(32, 8, 1);
  const float inv_sqrt_e = 0.03125f;   // 1/sqrt(1024)
  const float* nf = nullptr;

  // 1) cast x -> bf16
  cast_f32_bf16<<<16384, 256, 0, stream>>>(x, wsXB);

  // 2) weights -> bf16 transposed [N,K]  (Wq/Wk/Wv land contiguous)
  transpose_f32_bf16<<<dim3(32, 32, 1),  tb, 0, stream>>>(Wq, wsWQT, 1024, 1024);
  transpose_f32_bf16<<<dim3(32, 32, 1),  tb, 0, stream>>>(Wk, wsWKT, 1024, 1024);
  transpose_f32_bf16<<<dim3(32, 32, 1),  tb, 0, stream>>>(Wv, wsWVT, 1024, 1024);
  transpose_f32_bf16<<<dim3(32, 32, 1),  tb, 0, stream>>>(Wo, wsWOT, 1024, 1024);
  transpose_f32_bf16<<<dim3(128, 32, 1), tb, 0, stream>>>(W1, wsW1T, 1024, 4096);
  transpose_f32_bf16<<<dim3(32, 128, 1), tb, 0, stream>>>(W2, wsW2T, 4096, 1024);

  // 3) fused QKV: [16384,1024] x [3072,1024]^T, epilogue routes to Q/K/V + bias
  gemm256<5><<<dim3(24, 64, 1), 512, 0, stream>>>(wsXB, wsWQT, wsQ, bq, bk, bv, nf,
                                                  16384, 3072, 1024, 1.f, 0, 0, 0);

  // 4) V -> V^T per batch: [2048,1024] -> [1024,2048]
  transpose_bf16_bf16<<<dim3(32, 64, 8), tb, 0, stream>>>(wsV, wsVT, 2048, 1024, 2048LL * 1024, 1024LL * 2048);

  // 5) P~ = exp(Q K^T / 32) : batched, epilogue exp (no max-sub; |s| <= ~2)
  gemm256<3><<<dim3(16, 8, 8), 512, 0, stream>>>(wsQ, wsK, wsS, nf, nf, nf, nf,
                                                 2048, 2048, 1024, inv_sqrt_e,
                                                 2048LL * 1024, 2048LL * 1024, 2048LL * 2048);
  // 6) linv[row] = 1 / rowsum(P~)
  rowinv2048<<<16384, 256, 0, stream>>>(wsS, wsLINV);

  // 7) attn_out = (P~ V) * linv : batched, epilogue row-normalize (per-batch linv)
  gemm256<4><<<dim3(8, 8, 8), 512, 0, stream>>>(wsS, wsVT, wsAO, nf, nf, nf, wsLINV,
                                                2048, 1024, 2048, 1.f,
                                                2048LL * 2048, 1024LL * 2048, 2048LL * 1024);
  // 8) out-proj  (AO2 overwrites linv region only after PV completed, stream-ordered)
  gemm256<1><<<dim3(8, 64, 1), 512, 0, stream>>>(wsAO, wsWOT, wsAO2, bo, nf, nf, nf,
                                                 16384, 1024, 1024, 1.f, 0, 0, 0);

  // 9) h = LN(x + AO2)
  ln_add_f32bf16<<<16384, 256, 0, stream>>>(x, wsAO2, g1, b1, wsH);

  // 10) HID = relu(h W1 + bf1) : [16384,1024] x [1024,4096]
  gemm256<2><<<dim3(32, 64, 1), 512, 0, stream>>>(wsH, wsW1T, wsHID, bf1, nf, nf, nf,
                                                  16384, 4096, 1024, 1.f, 0, 0, 0);

  // 11) FFN = HID W2 + bf2 : [16384,4096] x [4096,1024]
  gemm256<1><<<dim3(8, 64, 1), 512, 0, stream>>>(wsHID, wsW2T, wsFFN, bf2, nf, nf, nf,
                                                 16384, 1024, 4096, 1.f, 0, 0, 0);

  // 12) out = LN(h + FFN), fp32
  ln_add_bf16bf16<<<16384, 256, 0, stream>>>(wsH, wsFFN, g2, b2, out);

  (void)in_sizes; (void)n_in; (void)out_size; (void)ws_size;
}

// Round 10
// 666.619 us; speedup vs baseline: 1.0339x; 1.0314x over previous
//
#include <hip/hip_runtime.h>

// BERT encoder block fwd. R10: revert GEMM core to R7 (256^2 4-phase, 1 blk/CU —
// best known 659us; R8/R9 occupancy-2 experiments refuted: conflicts fixed but L2
// thrash doubled FETCH). New in R10: rowsum folded into scores epilogue (shfl
// reduce + atomicAdd per row in the coalesced-store loop); PV divides by l.
// lsum lives at V-region start (dead between VT transpose and HID); memset'd
// stream-ordered. rowinv2048 kernel deleted.

typedef __attribute__((ext_vector_type(4))) float  f32x4;
typedef __attribute__((ext_vector_type(8))) short  s16x8;
typedef __attribute__((ext_vector_type(4))) short  s16x4;
typedef unsigned short u16;
typedef unsigned int   u32;

__device__ __forceinline__ float bf2f(short s) {
  u32 u = ((u32)(u16)s) << 16;
  float f; __builtin_memcpy(&f, &u, 4); return f;
}
__device__ __forceinline__ short f2bf(float f) {
  u32 u; __builtin_memcpy(&u, &f, 4);
  u32 r = (u + 0x7fffu + ((u >> 16) & 1u)) >> 16;   // RNE
  return (short)(u16)r;
}

// async global->LDS, 16B/lane; LDS dest must be wave-uniform base + lane*16
__device__ __forceinline__ void gload16(const void* g, void* l) {
  __builtin_amdgcn_global_load_lds(
      (const __attribute__((address_space(1))) u32*)g,
      (__attribute__((address_space(3))) u32*)l, 16, 0, 0);
}

// stage one 128-row half of a 256x64 bf16 tile (2 gload16/thread, 512 threads)
__device__ __forceinline__ void stage_half(const char* gop, long long ldb,
                                           long long rowbase, int tt, int h,
                                           u16* ldsop, int tid) {
#pragma unroll
  for (int l = 0; l < 2; ++l) {
    const int o   = (l * 512 + tid) * 16;          // linear byte offset in half (16 KiB)
    const int rih = o >> 7;                        // row in half 0..127
    const int scb = (o & 127) ^ ((rih & 7) << 4);  // inverse-swizzled source col-byte
    gload16(gop + (rowbase + h * 128 + rih) * ldb + (long long)tt * 128 + scb,
            (char*)ldsop + h * 16384 + o);
  }
}

#define SABUF(c) (SMEM + (c) * 16384)
#define SBBUF(c) (SMEM + 32768 + (c) * 16384)

#define RD_A(MH) do { _Pragma("unroll") for (int mi = 0; mi < 4; ++mi) { \
    const int row_ = wm * 64 + (MH) * 128 + mi * 16 + lr; \
    const int sw_ = (row_ & 7) << 4; const int rb_ = row_ << 7; \
    _Pragma("unroll") for (int kk = 0; kk < 2; ++kk) \
      af[mi][kk] = *(const s16x8*)(pa + rb_ + (((kk << 6) | (kg << 4)) ^ sw_)); } } while (0)

#define RD_B(NH) do { _Pragma("unroll") for (int nj = 0; nj < 2; ++nj) { \
    const int row_ = wn * 32 + (NH) * 128 + nj * 16 + lr; \
    const int sw_ = (row_ & 7) << 4; const int rb_ = row_ << 7; \
    _Pragma("unroll") for (int kk = 0; kk < 2; ++kk) \
      bf[NH][nj][kk] = *(const s16x8*)(pb + rb_ + (((kk << 6) | (kg << 4)) ^ sw_)); } } while (0)

#define MM(MH, NH) do { _Pragma("unroll") for (int kk = 0; kk < 2; ++kk) \
    _Pragma("unroll") for (int mi = 0; mi < 4; ++mi) \
    _Pragma("unroll") for (int nj = 0; nj < 2; ++nj) \
      acc[(MH) * 4 + mi][(NH) * 2 + nj] = __builtin_amdgcn_mfma_f32_16x16x32_bf16( \
        af[mi][kk], bf[NH][nj][kk], acc[(MH) * 4 + mi][(NH) * 2 + nj], 0, 0, 0); } while (0)

#define PH_SYNC do { __builtin_amdgcn_s_barrier(); \
    asm volatile("s_waitcnt lgkmcnt(0)"); \
    __builtin_amdgcn_sched_barrier(0); } while (0)

// Epilogue MODE: 1 = +bias; 2 = relu(+bias); 3 = exp(scale*acc) + row-sum atomics
//               into lsum [scores]; 4 = acc / lsum[z*M+row] [PV]; 5 = +bias,
//               route col>>10 to three [*,1024] outputs spaced 16777216 (QKV).
template<int MODE>
__global__ __launch_bounds__(512, 2)
void gemm256(const u16* __restrict__ A, const u16* __restrict__ BT,
             u16* __restrict__ C,
             const float* __restrict__ bias0, const float* __restrict__ bias1,
             const float* __restrict__ bias2, float* __restrict__ lsum,
             int M, int N, int K, float scale,
             long long sA, long long sB, long long sC) {
  __shared__ u16 SMEM[65536];   // K-loop: SA dbuf | SB dbuf (4 x 16K u16); epilogue: [256][256]

  // T1: bijective XCD swizzle over flattened 3D grid (m204)
  const int gx = gridDim.x, gy = gridDim.y;
  const int nwg = gx * gy * gridDim.z;
  const int orig = (blockIdx.z * gy + blockIdx.y) * gx + blockIdx.x;
  const int q = nwg >> 3, r8 = nwg & 7;
  const int xcd = orig & 7, pos = orig >> 3;
  const int wg = (xcd < r8 ? xcd * (q + 1) : r8 * (q + 1) + (xcd - r8) * q) + pos;
  const int bz = wg / (gx * gy);
  const int rem = wg % (gx * gy);
  const long long bm = (long long)(rem / gx) * 256;
  const long long bn = (long long)(rem % gx) * 256;

  const char* Ag = (const char*)(A + (long long)bz * sA);
  const char* Bg = (const char*)(BT + (long long)bz * sB);
  u16* Cb = C + (long long)bz * sC;
  const long long ldb = (long long)K * 2;

  const int tid = threadIdx.x;
  const int lane = tid & 63, wid = tid >> 6;
  const int lr = lane & 15, kg = lane >> 4;
  const int wm = wid >> 2, wn = wid & 3;
  const int NT = K >> 6;

  f32x4 acc[8][4] = {};
  s16x8 af[4][2];
  s16x8 bf[2][2][2];

  // prologue: T0 fully + T1 first halves; wait T0 (4 loads may stay in flight)
  stage_half(Ag, ldb, bm, 0, 0, SABUF(0), tid);
  stage_half(Bg, ldb, bn, 0, 0, SBBUF(0), tid);
  stage_half(Ag, ldb, bm, 0, 1, SABUF(0), tid);
  stage_half(Bg, ldb, bn, 0, 1, SBBUF(0), tid);
  stage_half(Ag, ldb, bm, 1, 0, SABUF(1), tid);
  stage_half(Bg, ldb, bn, 1, 0, SBBUF(1), tid);
  asm volatile("s_waitcnt vmcnt(4)");
  __builtin_amdgcn_s_barrier();

  for (int T = 0; T < NT; ++T) {
    const int c = T & 1, cn = c ^ 1;
    const char* pa = (const char*)SABUF(c);
    const char* pb = (const char*)SBBUF(c);

    // ---- phase 0: quadrant (mh0, nh0); stage (T+1).Ah1
    RD_A(0); RD_B(0);
    if (T + 1 < NT) stage_half(Ag, ldb, bm, T + 1, 1, SABUF(cn), tid);
    PH_SYNC;
    __builtin_amdgcn_s_setprio(1); MM(0, 0); __builtin_amdgcn_s_setprio(0);
    __builtin_amdgcn_s_barrier();

    // ---- phase 1: (mh0, nh1); stage (T+1).Bh1
    RD_B(1);
    if (T + 1 < NT) stage_half(Bg, ldb, bn, T + 1, 1, SBBUF(cn), tid);
    PH_SYNC;
    __builtin_amdgcn_s_setprio(1); MM(0, 1); __builtin_amdgcn_s_setprio(0);
    __builtin_amdgcn_s_barrier();

    // ---- phase 2: (mh1, nh0); stage (T+2).Ah0
    RD_A(1);
    if (T + 2 < NT) stage_half(Ag, ldb, bm, T + 2, 0, SABUF(c), tid);
    PH_SYNC;
    __builtin_amdgcn_s_setprio(1); MM(1, 0); __builtin_amdgcn_s_setprio(0);
    __builtin_amdgcn_s_barrier();

    // ---- phase 3: (mh1, nh1); stage (T+2).Bh0; counted boundary wait
    if (T + 2 < NT) stage_half(Bg, ldb, bn, T + 2, 0, SBBUF(c), tid);
    PH_SYNC;
    __builtin_amdgcn_s_setprio(1); MM(1, 1); __builtin_amdgcn_s_setprio(0);
    if (T + 2 < NT)      { asm volatile("s_waitcnt vmcnt(4)"); }
    else if (T + 1 < NT) { asm volatile("s_waitcnt vmcnt(0)"); }
    __builtin_amdgcn_s_barrier();
  }

  // ---- epilogue: acc -> LDS (swizzled conflict-free) -> coalesced 16B stores.
  // Write swizzle: element col' = col ^ (kg<<4)  (kg = row bits 2..3).
  const long long zM = (long long)bz * M;
  u16* obase; long long ldc, bnl;
  const float* bptr = bias0;
  if (MODE == 5) {
    const int sel = (int)(bn >> 10);
    obase = C + (long long)sel * 16777216;
    ldc = 1024; bnl = bn & 1023;
    bptr = (sel == 0 ? bias0 : sel == 1 ? bias1 : bias2);
  } else { obase = Cb; ldc = N; bnl = bn; }

#pragma unroll
  for (int nh = 0; nh < 2; ++nh)
#pragma unroll
    for (int nj = 0; nj < 2; ++nj) {
      const int col = wn * 32 + nh * 128 + nj * 16 + lr;     // local col 0..255
      float bv = 0.f;
      if (MODE == 1 || MODE == 2 || MODE == 5) bv = bptr[bnl + col];
#pragma unroll
      for (int mh = 0; mh < 2; ++mh)
#pragma unroll
        for (int mi = 0; mi < 4; ++mi) {
          const int row0 = wm * 64 + mh * 128 + mi * 16 + kg * 4;  // local row
#pragma unroll
          for (int r = 0; r < 4; ++r) {
            float v = acc[mh * 4 + mi][nh * 2 + nj][r];
            if (MODE == 1 || MODE == 2 || MODE == 5) v = v * scale + bv;
            if (MODE == 2) v = fmaxf(v, 0.f);
            if (MODE == 3) v = __expf(v * scale);
            if (MODE == 4) v = v / lsum[zM + bm + row0 + r];
            SMEM[(row0 + r) * 256 + (col ^ (kg << 4))] = (u16)f2bf(v);
          }
        }
    }
  __syncthreads();
#pragma unroll
  for (int i = 0; i < 16; ++i) {
    const int o   = (i * 512 + tid) * 16;          // byte offset in 128KiB tile
    const int row = o >> 9;                        // local row (512 B/row)
    const int wb  = o & 511;                       // byte-in-row = local col*2
    const int gs  = (wb >> 4) ^ (((row >> 2) & 3) << 1);  // inverse granule swizzle
    s16x8 d = *(const s16x8*)((const char*)SMEM + row * 512 + (gs << 4));
    if (MODE == 3) {
      // fused row-sum: 32 lanes cover one full row (granule swizzle is a bijection)
      float s = 0.f;
#pragma unroll
      for (int j = 0; j < 8; ++j) s += bf2f(d[j]);
#pragma unroll
      for (int off = 1; off < 32; off <<= 1) s += __shfl_xor(s, off);
      if ((lane & 31) == 0) atomicAdd(&lsum[zM + bm + row], s);
    }
    *(s16x8*)((char*)obase + (((long long)bm + row) * ldc + bnl) * 2 + wb) = d;
  }
}

// ---------------------------------------------------------------- cast x -> bf16
__global__ __launch_bounds__(256) void cast_f32_bf16(const float* __restrict__ in,
                                                     u16* __restrict__ out) {
  long long i = (long long)blockIdx.x * 256 + threadIdx.x;
  f32x4 v = ((const f32x4*)in)[i];
  s16x4 o;
#pragma unroll
  for (int j = 0; j < 4; j++) o[j] = f2bf(v[j]);
  ((s16x4*)out)[i] = o;
}

// ------------------------------------------------- transpose fp32 [R,C] -> bf16 [C,R]
__global__ __launch_bounds__(256) void transpose_f32_bf16(const float* __restrict__ in,
                                                          u16* __restrict__ out,
                                                          int R, int C) {
  __shared__ float tile[32][33];
  const int tx = threadIdx.x, ty = threadIdx.y;
  const int r0 = blockIdx.y * 32, c0 = blockIdx.x * 32;
#pragma unroll
  for (int i = 0; i < 32; i += 8)
    tile[ty + i][tx] = in[(long long)(r0 + ty + i) * C + (c0 + tx)];
  __syncthreads();
#pragma unroll
  for (int i = 0; i < 32; i += 8)
    out[(long long)(c0 + ty + i) * R + (r0 + tx)] = (u16)f2bf(tile[tx][ty + i]);
}

// ------------------------------------------------- transpose bf16 [R,C] -> bf16 [C,R] (batched)
__global__ __launch_bounds__(256) void transpose_bf16_bf16(const u16* __restrict__ in,
                                                           u16* __restrict__ out,
                                                           int R, int C,
                                                           long long isb, long long osb) {
  __shared__ u16 tile[32][33];
  in  += (long long)blockIdx.z * isb;
  out += (long long)blockIdx.z * osb;
  const int tx = threadIdx.x, ty = threadIdx.y;
  const int r0 = blockIdx.y * 32, c0 = blockIdx.x * 32;
#pragma unroll
  for (int i = 0; i < 32; i += 8)
    tile[ty + i][tx] = in[(long long)(r0 + ty + i) * C + (c0 + tx)];
  __syncthreads();
#pragma unroll
  for (int i = 0; i < 32; i += 8)
    out[(long long)(c0 + ty + i) * R + (r0 + tx)] = tile[tx][ty + i];
}

// ---------------------------------------------------------------- LN(x_f32 + a_bf16) -> bf16
__global__ __launch_bounds__(256) void ln_add_f32bf16(const float* __restrict__ x,
                                                      const u16* __restrict__ a,
                                                      const float* __restrict__ g,
                                                      const float* __restrict__ be,
                                                      u16* __restrict__ out) {
  const long long row = blockIdx.x;
  const int t = threadIdx.x;
  f32x4 xv = ((const f32x4*)(x + row * 1024))[t];
  s16x4 av = ((const s16x4*)(a + row * 1024))[t];
  float v[4]; float sum = 0.f, ss = 0.f;
#pragma unroll
  for (int j = 0; j < 4; j++) { v[j] = xv[j] + bf2f(av[j]); sum += v[j]; ss += v[j] * v[j]; }
#pragma unroll
  for (int off = 32; off > 0; off >>= 1) { sum += __shfl_xor(sum, off); ss += __shfl_xor(ss, off); }
  __shared__ float red[8];
  if ((t & 63) == 0) { red[t >> 6] = sum; red[4 + (t >> 6)] = ss; }
  __syncthreads();
  sum = (red[0] + red[1]) + (red[2] + red[3]);
  ss  = (red[4] + red[5]) + (red[6] + red[7]);
  const float mu   = sum * (1.f / 1024.f);
  const float var  = ss * (1.f / 1024.f) - mu * mu;
  const float rstd = rsqrtf(var + 1e-5f);
  s16x4 o;
#pragma unroll
  for (int j = 0; j < 4; j++) {
    const int c = t * 4 + j;
    o[j] = f2bf((v[j] - mu) * rstd * g[c] + be[c]);
  }
  *(s16x4*)&out[row * 1024 + t * 4] = o;
}

// ---------------------------------------------------------------- LN(h_bf16 + f_bf16) -> fp32
__global__ __launch_bounds__(256) void ln_add_bf16bf16(const u16* __restrict__ h,
                                                       const u16* __restrict__ f,
                                                       const float* __restrict__ g,
                                                       const float* __restrict__ be,
                                                       float* __restrict__ out) {
  const long long row = blockIdx.x;
  const int t = threadIdx.x;
  s16x4 hv = ((const s16x4*)(h + row * 1024))[t];
  s16x4 fv = ((const s16x4*)(f + row * 1024))[t];
  float v[4]; float sum = 0.f, ss = 0.f;
#pragma unroll
  for (int j = 0; j < 4; j++) { v[j] = bf2f(hv[j]) + bf2f(fv[j]); sum += v[j]; ss += v[j] * v[j]; }
#pragma unroll
  for (int off = 32; off > 0; off >>= 1) { sum += __shfl_xor(sum, off); ss += __shfl_xor(ss, off); }
  __shared__ float red[8];
  if ((t & 63) == 0) { red[t >> 6] = sum; red[4 + (t >> 6)] = ss; }
  __syncthreads();
  sum = (red[0] + red[1]) + (red[2] + red[3]);
  ss  = (red[4] + red[5]) + (red[6] + red[7]);
  const float mu   = sum * (1.f / 1024.f);
  const float var  = ss * (1.f / 1024.f) - mu * mu;
  const float rstd = rsqrtf(var + 1e-5f);
  f32x4 o;
#pragma unroll
  for (int j = 0; j < 4; j++) {
    const int c = t * 4 + j;
    o[j] = (v[j] - mu) * rstd * g[c] + be[c];
  }
  ((f32x4*)(out + row * 1024))[t] = o;
}

// ---------------------------------------------------------------- launcher
extern "C" void kernel_launch(void* const* d_in, const int* in_sizes, int n_in,
                              void* d_out, int out_size, void* d_ws, size_t ws_size,
                              hipStream_t stream) {
  const float* x   = (const float*)d_in[0];
  const float* Wq  = (const float*)d_in[1];
  const float* bq  = (const float*)d_in[2];
  const float* Wk  = (const float*)d_in[3];
  const float* bk  = (const float*)d_in[4];
  const float* Wv  = (const float*)d_in[5];
  const float* bv  = (const float*)d_in[6];
  const float* Wo  = (const float*)d_in[7];
  const float* bo  = (const float*)d_in[8];
  const float* g1  = (const float*)d_in[9];
  const float* b1  = (const float*)d_in[10];
  const float* g2  = (const float*)d_in[11];
  const float* b2  = (const float*)d_in[12];
  const float* W1  = (const float*)d_in[13];
  const float* bf1 = (const float*)d_in[14];
  const float* W2  = (const float*)d_in[15];
  const float* bf2 = (const float*)d_in[16];
  float* out = (float*)d_out;

  // workspace layout (bytes), ~248 MiB, with aliasing.
  // weights 0..25165824 (WQT/WKT/WVT contiguous = fused [3072,1024]); XB 32MiB;
  // Q 32MiB; K 32MiB; V 32MiB; VT 32MiB; S 64MiB.
  // Aliases: AO->XB, AO2->Q, H->K, HID->[V..S end] (128MiB), FFN->XB.
  // lsum (16384 f32, 64KB) -> V region start: V dead after VT transpose, until HID.
  char* ws = (char*)d_ws;
  u16* wsWQT = (u16*)(ws + 0);           // fused QKV weight base [3072,1024]
  u16* wsWKT = (u16*)(ws + 2097152);
  u16* wsWVT = (u16*)(ws + 4194304);
  u16* wsWOT = (u16*)(ws + 6291456);
  u16* wsW1T = (u16*)(ws + 8388608);     // [4096,1024] bf16, 8 MiB
  u16* wsW2T = (u16*)(ws + 16777216);    // [1024,4096] bf16, 8 MiB
  u16* wsXB  = (u16*)(ws + 25165824);    // [16384,1024] bf16 tokens, 32 MiB
  u16* wsQ   = (u16*)(ws + 58720256);    // Q/K/V contiguous (QKV epilogue routing)
  u16* wsK   = (u16*)(ws + 92274688);
  u16* wsV   = (u16*)(ws + 125829120);
  u16* wsVT  = (u16*)(ws + 159383552);   // [8][1024,2048] bf16, 32 MiB
  u16* wsS   = (u16*)(ws + 192937984);   // [8][2048,2048] bf16 P~ = exp(s), 64 MiB
  u16* wsAO  = wsXB;
  u16* wsAO2 = wsQ;
  u16* wsH   = wsK;
  u16* wsHID = wsV;                      // [16384,4096] bf16, 128 MiB (covers V,VT,S)
  u16* wsFFN = wsXB;
  float* wsLSUM = (float*)wsV;           // 64 KiB, live steps 5-7 only

  const dim3 tb(32, 8, 1);
  const float inv_sqrt_e = 0.03125f;   // 1/sqrt(1024)
  const float* nf = nullptr;
  float* nfm = nullptr;

  // 1) cast x -> bf16
  cast_f32_bf16<<<16384, 256, 0, stream>>>(x, wsXB);

  // 2) weights -> bf16 transposed [N,K]  (Wq/Wk/Wv land contiguous)
  transpose_f32_bf16<<<dim3(32, 32, 1),  tb, 0, stream>>>(Wq, wsWQT, 1024, 1024);
  transpose_f32_bf16<<<dim3(32, 32, 1),  tb, 0, stream>>>(Wk, wsWKT, 1024, 1024);
  transpose_f32_bf16<<<dim3(32, 32, 1),  tb, 0, stream>>>(Wv, wsWVT, 1024, 1024);
  transpose_f32_bf16<<<dim3(32, 32, 1),  tb, 0, stream>>>(Wo, wsWOT, 1024, 1024);
  transpose_f32_bf16<<<dim3(128, 32, 1), tb, 0, stream>>>(W1, wsW1T, 1024, 4096);
  transpose_f32_bf16<<<dim3(32, 128, 1), tb, 0, stream>>>(W2, wsW2T, 4096, 1024);

  // 3) fused QKV: [16384,1024] x [3072,1024]^T, epilogue routes to Q/K/V + bias
  gemm256<5><<<dim3(12, 64, 1), 512, 0, stream>>>(wsXB, wsWQT, wsQ, bq, bk, bv, nfm,
                                                  16384, 3072, 1024, 1.f, 0, 0, 0);

  // 4) V -> V^T per batch: [2048,1024] -> [1024,2048]; then zero lsum (V now dead)
  transpose_bf16_bf16<<<dim3(32, 64, 8), tb, 0, stream>>>(wsV, wsVT, 2048, 1024, 2048LL * 1024, 1024LL * 2048);
  hipMemsetAsync(wsLSUM, 0, 16384 * sizeof(float), stream);

  // 5) P~ = exp(Q K^T / 32), fused row-sum atomics into lsum
  gemm256<3><<<dim3(8, 8, 8), 512, 0, stream>>>(wsQ, wsK, wsS, nf, nf, nf, wsLSUM,
                                                2048, 2048, 1024, inv_sqrt_e,
                                                2048LL * 1024, 2048LL * 1024, 2048LL * 2048);

  // 6) attn_out = (P~ V) / l : batched, epilogue row-normalize (per-batch lsum)
  gemm256<4><<<dim3(4, 8, 8), 512, 0, stream>>>(wsS, wsVT, wsAO, nf, nf, nf, wsLSUM,
                                                2048, 1024, 2048, 1.f,
                                                2048LL * 2048, 1024LL * 2048, 2048LL * 1024);
  // 7) out-proj
  gemm256<1><<<dim3(4, 64, 1), 512, 0, stream>>>(wsAO, wsWOT, wsAO2, bo, nf, nf, nfm,
                                                 16384, 1024, 1024, 1.f, 0, 0, 0);

  // 8) h = LN(x + AO2)
  ln_add_f32bf16<<<16384, 256, 0, stream>>>(x, wsAO2, g1, b1, wsH);

  // 9) HID = relu(h W1 + bf1) : [16384,1024] x [1024,4096]
  gemm256<2><<<dim3(16, 64, 1), 512, 0, stream>>>(wsH, wsW1T, wsHID, bf1, nf, nf, nfm,
                                                  16384, 4096, 1024, 1.f, 0, 0, 0);

  // 10) FFN = HID W2 + bf2 : [16384,4096] x [4096,1024]
  gemm256<1><<<dim3(4, 64, 1), 512, 0, stream>>>(wsHID, wsW2T, wsFFN, bf2, nf, nf, nfm,
                                                 16384, 1024, 4096, 1.f, 0, 0, 0);

  // 11) out = LN(h + FFN), fp32
  ln_add_bf16bf16<<<16384, 256, 0, stream>>>(wsH, wsFFN, g2, b2, out);

  (void)in_sizes; (void)n_in; (void)out_size; (void)ws_size;
}

// Round 11
// 614.304 us; speedup vs baseline: 1.1219x; 1.0852x over previous
//
#include <hip/hip_runtime.h>

// BERT encoder block fwd. R11 (consolidation on R10 core):
//  - prep kernel merges cast + 6 weight transposes (13 -> 8 dispatches)
//  - LN1 reads bf16 XB instead of f32 x (saves 32MB read); LN kernels unified
//  - ws re-layout: AO->Q, AO2/H/FFN->S region, HID->XB..V (128MiB), lsum->V start
// GEMM core unchanged from R10: 256^2 4-phase, T1-T5, LDS-staged coalesced
// epilogue, fused rowsum atomics in scores, PV divides by lsum.

typedef __attribute__((ext_vector_type(4))) float  f32x4;
typedef __attribute__((ext_vector_type(8))) short  s16x8;
typedef __attribute__((ext_vector_type(4))) short  s16x4;
typedef unsigned short u16;
typedef unsigned int   u32;

__device__ __forceinline__ float bf2f(short s) {
  u32 u = ((u32)(u16)s) << 16;
  float f; __builtin_memcpy(&f, &u, 4); return f;
}
__device__ __forceinline__ short f2bf(float f) {
  u32 u; __builtin_memcpy(&u, &f, 4);
  u32 r = (u + 0x7fffu + ((u >> 16) & 1u)) >> 16;   // RNE
  return (short)(u16)r;
}

// async global->LDS, 16B/lane; LDS dest must be wave-uniform base + lane*16
__device__ __forceinline__ void gload16(const void* g, void* l) {
  __builtin_amdgcn_global_load_lds(
      (const __attribute__((address_space(1))) u32*)g,
      (__attribute__((address_space(3))) u32*)l, 16, 0, 0);
}

// stage one 128-row half of a 256x64 bf16 tile (2 gload16/thread, 512 threads)
__device__ __forceinline__ void stage_half(const char* gop, long long ldb,
                                           long long rowbase, int tt, int h,
                                           u16* ldsop, int tid) {
#pragma unroll
  for (int l = 0; l < 2; ++l) {
    const int o   = (l * 512 + tid) * 16;          // linear byte offset in half (16 KiB)
    const int rih = o >> 7;                        // row in half 0..127
    const int scb = (o & 127) ^ ((rih & 7) << 4);  // inverse-swizzled source col-byte
    gload16(gop + (rowbase + h * 128 + rih) * ldb + (long long)tt * 128 + scb,
            (char*)ldsop + h * 16384 + o);
  }
}

#define SABUF(c) (SMEM + (c) * 16384)
#define SBBUF(c) (SMEM + 32768 + (c) * 16384)

#define RD_A(MH) do { _Pragma("unroll") for (int mi = 0; mi < 4; ++mi) { \
    const int row_ = wm * 64 + (MH) * 128 + mi * 16 + lr; \
    const int sw_ = (row_ & 7) << 4; const int rb_ = row_ << 7; \
    _Pragma("unroll") for (int kk = 0; kk < 2; ++kk) \
      af[mi][kk] = *(const s16x8*)(pa + rb_ + (((kk << 6) | (kg << 4)) ^ sw_)); } } while (0)

#define RD_B(NH) do { _Pragma("unroll") for (int nj = 0; nj < 2; ++nj) { \
    const int row_ = wn * 32 + (NH) * 128 + nj * 16 + lr; \
    const int sw_ = (row_ & 7) << 4; const int rb_ = row_ << 7; \
    _Pragma("unroll") for (int kk = 0; kk < 2; ++kk) \
      bf[NH][nj][kk] = *(const s16x8*)(pb + rb_ + (((kk << 6) | (kg << 4)) ^ sw_)); } } while (0)

#define MM(MH, NH) do { _Pragma("unroll") for (int kk = 0; kk < 2; ++kk) \
    _Pragma("unroll") for (int mi = 0; mi < 4; ++mi) \
    _Pragma("unroll") for (int nj = 0; nj < 2; ++nj) \
      acc[(MH) * 4 + mi][(NH) * 2 + nj] = __builtin_amdgcn_mfma_f32_16x16x32_bf16( \
        af[mi][kk], bf[NH][nj][kk], acc[(MH) * 4 + mi][(NH) * 2 + nj], 0, 0, 0); } while (0)

#define PH_SYNC do { __builtin_amdgcn_s_barrier(); \
    asm volatile("s_waitcnt lgkmcnt(0)"); \
    __builtin_amdgcn_sched_barrier(0); } while (0)

// Epilogue MODE: 1 = +bias; 2 = relu(+bias); 3 = exp(scale*acc) + row-sum atomics
//               into lsum [scores]; 4 = acc / lsum[z*M+row] [PV]; 5 = +bias,
//               route col>>10 to three [*,1024] outputs spaced 16777216 (QKV).
template<int MODE>
__global__ __launch_bounds__(512, 2)
void gemm256(const u16* __restrict__ A, const u16* __restrict__ BT,
             u16* __restrict__ C,
             const float* __restrict__ bias0, const float* __restrict__ bias1,
             const float* __restrict__ bias2, float* __restrict__ lsum,
             int M, int N, int K, float scale,
             long long sA, long long sB, long long sC) {
  __shared__ u16 SMEM[65536];   // K-loop: SA dbuf | SB dbuf (4 x 16K u16); epilogue: [256][256]

  // T1: bijective XCD swizzle over flattened 3D grid (m204)
  const int gx = gridDim.x, gy = gridDim.y;
  const int nwg = gx * gy * gridDim.z;
  const int orig = (blockIdx.z * gy + blockIdx.y) * gx + blockIdx.x;
  const int q = nwg >> 3, r8 = nwg & 7;
  const int xcd = orig & 7, pos = orig >> 3;
  const int wg = (xcd < r8 ? xcd * (q + 1) : r8 * (q + 1) + (xcd - r8) * q) + pos;
  const int bz = wg / (gx * gy);
  const int rem = wg % (gx * gy);
  const long long bm = (long long)(rem / gx) * 256;
  const long long bn = (long long)(rem % gx) * 256;

  const char* Ag = (const char*)(A + (long long)bz * sA);
  const char* Bg = (const char*)(BT + (long long)bz * sB);
  u16* Cb = C + (long long)bz * sC;
  const long long ldb = (long long)K * 2;

  const int tid = threadIdx.x;
  const int lane = tid & 63, wid = tid >> 6;
  const int lr = lane & 15, kg = lane >> 4;
  const int wm = wid >> 2, wn = wid & 3;
  const int NT = K >> 6;

  f32x4 acc[8][4] = {};
  s16x8 af[4][2];
  s16x8 bf[2][2][2];

  // prologue: T0 fully + T1 first halves; wait T0 (4 loads may stay in flight)
  stage_half(Ag, ldb, bm, 0, 0, SABUF(0), tid);
  stage_half(Bg, ldb, bn, 0, 0, SBBUF(0), tid);
  stage_half(Ag, ldb, bm, 0, 1, SABUF(0), tid);
  stage_half(Bg, ldb, bn, 0, 1, SBBUF(0), tid);
  stage_half(Ag, ldb, bm, 1, 0, SABUF(1), tid);
  stage_half(Bg, ldb, bn, 1, 0, SBBUF(1), tid);
  asm volatile("s_waitcnt vmcnt(4)");
  __builtin_amdgcn_s_barrier();

  for (int T = 0; T < NT; ++T) {
    const int c = T & 1, cn = c ^ 1;
    const char* pa = (const char*)SABUF(c);
    const char* pb = (const char*)SBBUF(c);

    // ---- phase 0: quadrant (mh0, nh0); stage (T+1).Ah1
    RD_A(0); RD_B(0);
    if (T + 1 < NT) stage_half(Ag, ldb, bm, T + 1, 1, SABUF(cn), tid);
    PH_SYNC;
    __builtin_amdgcn_s_setprio(1); MM(0, 0); __builtin_amdgcn_s_setprio(0);
    __builtin_amdgcn_s_barrier();

    // ---- phase 1: (mh0, nh1); stage (T+1).Bh1
    RD_B(1);
    if (T + 1 < NT) stage_half(Bg, ldb, bn, T + 1, 1, SBBUF(cn), tid);
    PH_SYNC;
    __builtin_amdgcn_s_setprio(1); MM(0, 1); __builtin_amdgcn_s_setprio(0);
    __builtin_amdgcn_s_barrier();

    // ---- phase 2: (mh1, nh0); stage (T+2).Ah0
    RD_A(1);
    if (T + 2 < NT) stage_half(Ag, ldb, bm, T + 2, 0, SABUF(c), tid);
    PH_SYNC;
    __builtin_amdgcn_s_setprio(1); MM(1, 0); __builtin_amdgcn_s_setprio(0);
    __builtin_amdgcn_s_barrier();

    // ---- phase 3: (mh1, nh1); stage (T+2).Bh0; counted boundary wait
    if (T + 2 < NT) stage_half(Bg, ldb, bn, T + 2, 0, SBBUF(c), tid);
    PH_SYNC;
    __builtin_amdgcn_s_setprio(1); MM(1, 1); __builtin_amdgcn_s_setprio(0);
    if (T + 2 < NT)      { asm volatile("s_waitcnt vmcnt(4)"); }
    else if (T + 1 < NT) { asm volatile("s_waitcnt vmcnt(0)"); }
    __builtin_amdgcn_s_barrier();
  }

  // ---- epilogue: acc -> LDS (swizzled conflict-free) -> coalesced 16B stores.
  const long long zM = (long long)bz * M;
  u16* obase; long long ldc, bnl;
  const float* bptr = bias0;
  if (MODE == 5) {
    const int sel = (int)(bn >> 10);
    obase = C + (long long)sel * 16777216;
    ldc = 1024; bnl = bn & 1023;
    bptr = (sel == 0 ? bias0 : sel == 1 ? bias1 : bias2);
  } else { obase = Cb; ldc = N; bnl = bn; }

#pragma unroll
  for (int nh = 0; nh < 2; ++nh)
#pragma unroll
    for (int nj = 0; nj < 2; ++nj) {
      const int col = wn * 32 + nh * 128 + nj * 16 + lr;     // local col 0..255
      float bv = 0.f;
      if (MODE == 1 || MODE == 2 || MODE == 5) bv = bptr[bnl + col];
#pragma unroll
      for (int mh = 0; mh < 2; ++mh)
#pragma unroll
        for (int mi = 0; mi < 4; ++mi) {
          const int row0 = wm * 64 + mh * 128 + mi * 16 + kg * 4;  // local row
#pragma unroll
          for (int r = 0; r < 4; ++r) {
            float v = acc[mh * 4 + mi][nh * 2 + nj][r];
            if (MODE == 1 || MODE == 2 || MODE == 5) v = v * scale + bv;
            if (MODE == 2) v = fmaxf(v, 0.f);
            if (MODE == 3) v = __expf(v * scale);
            if (MODE == 4) v = v / lsum[zM + bm + row0 + r];
            SMEM[(row0 + r) * 256 + (col ^ (kg << 4))] = (u16)f2bf(v);
          }
        }
    }
  __syncthreads();
#pragma unroll
  for (int i = 0; i < 16; ++i) {
    const int o   = (i * 512 + tid) * 16;          // byte offset in 128KiB tile
    const int row = o >> 9;                        // local row (512 B/row)
    const int wb  = o & 511;                       // byte-in-row = local col*2
    const int gs  = (wb >> 4) ^ (((row >> 2) & 3) << 1);  // inverse granule swizzle
    s16x8 d = *(const s16x8*)((const char*)SMEM + row * 512 + (gs << 4));
    if (MODE == 3) {
      // fused row-sum: 32 lanes cover one full row (granule swizzle is a bijection)
      float s = 0.f;
#pragma unroll
      for (int j = 0; j < 8; ++j) s += bf2f(d[j]);
#pragma unroll
      for (int off = 1; off < 32; off <<= 1) s += __shfl_xor(s, off);
      if ((lane & 31) == 0) atomicAdd(&lsum[zM + bm + row], s);
    }
    *(s16x8*)((char*)obase + (((long long)bm + row) * ldc + bnl) * 2 + wb) = d;
  }
}

// ------------------------------------------- prep: cast x->bf16 + 6 weight transposes
// block-id ranges: [0,16384) cast; [16384,20480) Wq/Wk/Wv/Wo (1024 tiles each);
// [20480,24576) W1 (1024x4096); [24576,28672) W2 (4096x1024).
__global__ __launch_bounds__(256) void prep(
    const float* __restrict__ x,  u16* __restrict__ XB,
    const float* __restrict__ Wq, const float* __restrict__ Wk,
    const float* __restrict__ Wv, const float* __restrict__ Wo,
    const float* __restrict__ W1, const float* __restrict__ W2,
    u16* __restrict__ WQT, u16* __restrict__ WKT, u16* __restrict__ WVT,
    u16* __restrict__ WOT, u16* __restrict__ W1T, u16* __restrict__ W2T) {
  __shared__ float tile[32][33];
  const int bid = blockIdx.x;
  const int t = threadIdx.x;
  if (bid < 16384) {
    const long long i = (long long)bid * 256 + t;
    f32x4 v = ((const f32x4*)x)[i];
    s16x4 o;
#pragma unroll
    for (int j = 0; j < 4; j++) o[j] = f2bf(v[j]);
    ((s16x4*)XB)[i] = o;
    return;
  }
  const float* in; u16* out; int R, C, tb;
  if (bid < 20480) {
    const int w = (bid - 16384) >> 10;
    tb = (bid - 16384) & 1023;
    in  = (w == 0 ? Wq : w == 1 ? Wk : w == 2 ? Wv : Wo);
    out = (w == 0 ? WQT : w == 1 ? WKT : w == 2 ? WVT : WOT);
    R = 1024; C = 1024;
  } else if (bid < 24576) {
    tb = bid - 20480; in = W1; out = W1T; R = 1024; C = 4096;
  } else {
    tb = bid - 24576; in = W2; out = W2T; R = 4096; C = 1024;
  }
  const int tpr = C >> 5;
  const int r0 = (tb / tpr) * 32, c0 = (tb % tpr) * 32;
  const int tx = t & 31, ty = t >> 5;
#pragma unroll
  for (int i = 0; i < 32; i += 8)
    tile[ty + i][tx] = in[(long long)(r0 + ty + i) * C + (c0 + tx)];
  __syncthreads();
#pragma unroll
  for (int i = 0; i < 32; i += 8)
    out[(long long)(c0 + ty + i) * R + (r0 + tx)] = (u16)f2bf(tile[tx][ty + i]);
}

// ------------------------------------------------- transpose bf16 [R,C] -> bf16 [C,R] (batched)
__global__ __launch_bounds__(256) void transpose_bf16_bf16(const u16* __restrict__ in,
                                                           u16* __restrict__ out,
                                                           int R, int C,
                                                           long long isb, long long osb) {
  __shared__ u16 tile[32][33];
  in  += (long long)blockIdx.z * isb;
  out += (long long)blockIdx.z * osb;
  const int tx = threadIdx.x, ty = threadIdx.y;
  const int r0 = blockIdx.y * 32, c0 = blockIdx.x * 32;
#pragma unroll
  for (int i = 0; i < 32; i += 8)
    tile[ty + i][tx] = in[(long long)(r0 + ty + i) * C + (c0 + tx)];
  __syncthreads();
#pragma unroll
  for (int i = 0; i < 32; i += 8)
    out[(long long)(c0 + ty + i) * R + (r0 + tx)] = tile[tx][ty + i];
}

// ------------------------------------------- LN(a_bf16 + b_bf16) -> bf16 or f32
template<bool OUTF32>
__global__ __launch_bounds__(256) void ln_add(const u16* __restrict__ a,
                                              const u16* __restrict__ b,
                                              const float* __restrict__ g,
                                              const float* __restrict__ be,
                                              void* __restrict__ outp) {
  const long long row = blockIdx.x;
  const int t = threadIdx.x;
  s16x4 avv = ((const s16x4*)(a + row * 1024))[t];
  s16x4 bvv = ((const s16x4*)(b + row * 1024))[t];
  float v[4]; float sum = 0.f, ss = 0.f;
#pragma unroll
  for (int j = 0; j < 4; j++) { v[j] = bf2f(avv[j]) + bf2f(bvv[j]); sum += v[j]; ss += v[j] * v[j]; }
#pragma unroll
  for (int off = 32; off > 0; off >>= 1) { sum += __shfl_xor(sum, off); ss += __shfl_xor(ss, off); }
  __shared__ float red[8];
  if ((t & 63) == 0) { red[t >> 6] = sum; red[4 + (t >> 6)] = ss; }
  __syncthreads();
  sum = (red[0] + red[1]) + (red[2] + red[3]);
  ss  = (red[4] + red[5]) + (red[6] + red[7]);
  const float mu   = sum * (1.f / 1024.f);
  const float var  = ss * (1.f / 1024.f) - mu * mu;
  const float rstd = rsqrtf(var + 1e-5f);
  if (OUTF32) {
    f32x4 o;
#pragma unroll
    for (int j = 0; j < 4; j++) {
      const int c = t * 4 + j;
      o[j] = (v[j] - mu) * rstd * g[c] + be[c];
    }
    ((f32x4*)((float*)outp + row * 1024))[t] = o;
  } else {
    s16x4 o;
#pragma unroll
    for (int j = 0; j < 4; j++) {
      const int c = t * 4 + j;
      o[j] = f2bf((v[j] - mu) * rstd * g[c] + be[c]);
    }
    *(s16x4*)&((u16*)outp)[row * 1024 + t * 4] = o;
  }
}

// ---------------------------------------------------------------- launcher
extern "C" void kernel_launch(void* const* d_in, const int* in_sizes, int n_in,
                              void* d_out, int out_size, void* d_ws, size_t ws_size,
                              hipStream_t stream) {
  const float* x   = (const float*)d_in[0];
  const float* Wq  = (const float*)d_in[1];
  const float* bq  = (const float*)d_in[2];
  const float* Wk  = (const float*)d_in[3];
  const float* bk  = (const float*)d_in[4];
  const float* Wv  = (const float*)d_in[5];
  const float* bv  = (const float*)d_in[6];
  const float* Wo  = (const float*)d_in[7];
  const float* bo  = (const float*)d_in[8];
  const float* g1  = (const float*)d_in[9];
  const float* b1  = (const float*)d_in[10];
  const float* g2  = (const float*)d_in[11];
  const float* b2  = (const float*)d_in[12];
  const float* W1  = (const float*)d_in[13];
  const float* bf1 = (const float*)d_in[14];
  const float* W2  = (const float*)d_in[15];
  const float* bf2 = (const float*)d_in[16];
  float* out = (float*)d_out;

  // ws layout (bytes), 248 MiB total, liveness-checked aliasing:
  //  weights 0..25165824 (WQT/WKT/WVT contiguous for fused QKV)
  //  XB  = 25165824  (32MiB)  cast -> LN1
  //  Q   = 58720256  (32MiB)  QKV -> scores;  AO = Q after scores (PV -> Wo)
  //  K   = 92274688  (32MiB)  QKV -> scores
  //  V   = 125829120 (32MiB)  QKV -> VTt;     lsum = V start (memset -> PV)
  //  VT  = 159383552 (32MiB)  VTt -> PV
  //  S   = 192937984 (64MiB)  scores -> PV;   then AO2 = S+0 (Wo -> LN1),
  //                           H = S+32MiB (LN1 -> LN2), FFN = S+0 (FFN2 -> LN2)
  //  HID = XB..V end (128MiB) FFN1 -> FFN2 (XB/Q/K/V all dead by FFN1)
  char* ws = (char*)d_ws;
  u16* wsWQT = (u16*)(ws + 0);
  u16* wsWKT = (u16*)(ws + 2097152);
  u16* wsWVT = (u16*)(ws + 4194304);
  u16* wsWOT = (u16*)(ws + 6291456);
  u16* wsW1T = (u16*)(ws + 8388608);
  u16* wsW2T = (u16*)(ws + 16777216);
  u16* wsXB  = (u16*)(ws + 25165824);
  u16* wsQ   = (u16*)(ws + 58720256);
  u16* wsK   = (u16*)(ws + 92274688);
  u16* wsV   = (u16*)(ws + 125829120);
  u16* wsVT  = (u16*)(ws + 159383552);
  u16* wsS   = (u16*)(ws + 192937984);
  u16* wsAO  = wsQ;                       // PV out (Q dead after scores)
  u16* wsAO2 = wsS;                       // Wo out (S dead after PV)
  u16* wsH   = (u16*)(ws + 192937984 + 33554432);  // S + 32MiB
  u16* wsHID = wsXB;                      // 128MiB: XB+Q+K+V (all dead by FFN1)
  u16* wsFFN = wsS;                       // FFN2 out (AO2 dead after LN1)
  float* wsLSUM = (float*)wsV;            // 64KiB (V dead after VTt, until PV)

  const dim3 tb(32, 8, 1);
  const float inv_sqrt_e = 0.03125f;   // 1/sqrt(1024)
  const float* nf = nullptr;
  float* nfm = nullptr;

  // 1) prep: cast x->bf16 + all weight transposes (one kernel)
  prep<<<28672, 256, 0, stream>>>(x, wsXB, Wq, Wk, Wv, Wo, W1, W2,
                                  wsWQT, wsWKT, wsWVT, wsWOT, wsW1T, wsW2T);

  // 2) fused QKV: [16384,1024] x [3072,1024]^T, epilogue routes to Q/K/V + bias
  gemm256<5><<<dim3(12, 64, 1), 512, 0, stream>>>(wsXB, wsWQT, wsQ, bq, bk, bv, nfm,
                                                  16384, 3072, 1024, 1.f, 0, 0, 0);

  // 3) V -> V^T per batch; then zero lsum (V now dead)
  transpose_bf16_bf16<<<dim3(32, 64, 8), tb, 0, stream>>>(wsV, wsVT, 2048, 1024, 2048LL * 1024, 1024LL * 2048);
  hipMemsetAsync(wsLSUM, 0, 16384 * sizeof(float), stream);

  // 4) P~ = exp(Q K^T / 32), fused row-sum atomics into lsum
  gemm256<3><<<dim3(8, 8, 8), 512, 0, stream>>>(wsQ, wsK, wsS, nf, nf, nf, wsLSUM,
                                                2048, 2048, 1024, inv_sqrt_e,
                                                2048LL * 1024, 2048LL * 1024, 2048LL * 2048);

  // 5) attn_out = (P~ V) / l -> AO (=Q region)
  gemm256<4><<<dim3(4, 8, 8), 512, 0, stream>>>(wsS, wsVT, wsAO, nf, nf, nf, wsLSUM,
                                                2048, 1024, 2048, 1.f,
                                                2048LL * 2048, 1024LL * 2048, 2048LL * 1024);
  // 6) out-proj -> AO2 (=S region start)
  gemm256<1><<<dim3(4, 64, 1), 512, 0, stream>>>(wsAO, wsWOT, wsAO2, bo, nf, nf, nfm,
                                                 16384, 1024, 1024, 1.f, 0, 0, 0);

  // 7) h = LN(XB + AO2) -> H (bf16; XB is bf16 x, error << threshold)
  ln_add<false><<<16384, 256, 0, stream>>>(wsXB, wsAO2, g1, b1, wsH);

  // 8) HID = relu(h W1 + bf1) -> HID (=XB..V, 128MiB)
  gemm256<2><<<dim3(16, 64, 1), 512, 0, stream>>>(wsH, wsW1T, wsHID, bf1, nf, nf, nfm,
                                                  16384, 4096, 1024, 1.f, 0, 0, 0);

  // 9) FFN = HID W2 + bf2 -> FFN (=S start; H at S+32MiB untouched)
  gemm256<1><<<dim3(4, 64, 1), 512, 0, stream>>>(wsHID, wsW2T, wsFFN, bf2, nf, nf, nfm,
                                                 16384, 1024, 4096, 1.f, 0, 0, 0);

  // 10) out = LN(H + FFN), fp32
  ln_add<true><<<16384, 256, 0, stream>>>(wsH, wsFFN, g2, b2, out);

  (void)in_sizes; (void)n_in; (void)out_size; (void)ws_size;
}